// Round 3
// baseline (163.263 us; speedup 1.0000x reference)
//
#include <hip/hip_runtime.h>
#include <hip/hip_bf16.h>

#define BN 8192
#define DK 512
#define PN 4096
#define GY 8
#define PPB 512            // protos per gy slice
#define PG 16              // protos per group (one MFMA B-frag of 16 protos)
#define NG 32              // groups per slice; class = gy*16 + (g>>1)
#define SENT (-1.0e30f)
#define L2E 1.4426950408889634f
#define LN2 0.6931471805599453f

typedef __bf16 bf16x8 __attribute__((ext_vector_type(8)));
typedef __bf16 bf16x4 __attribute__((ext_vector_type(4)));
typedef float f32x4 __attribute__((ext_vector_type(4)));

__device__ __forceinline__ float ex2(float x) { return __builtin_amdgcn_exp2f(x); }

// ---------------------------------------------------------------------------
// K1: protos only — bf16 cast in CLASS-SORTED order + p_sq*log2e (sorted).
// Original proto p has class p%128; sorted row s = (p%128)*32 + p/128.
// ---------------------------------------------------------------------------
__global__ __launch_bounds__(256) void k_prep(const float* __restrict__ proto,
                                              __bf16* __restrict__ pB,
                                              float* __restrict__ p_sq) {
    int p  = blockIdx.x * 4 + (threadIdx.x >> 6);
    int ln = threadIdx.x & 63;
    const float* src = proto + (size_t)p * DK;
    float4 a = *(const float4*)(src + ln * 4);
    float4 b = *(const float4*)(src + 256 + ln * 4);
    float s = a.x * a.x + a.y * a.y + a.z * a.z + a.w * a.w
            + b.x * b.x + b.y * b.y + b.z * b.z + b.w * b.w;
#pragma unroll
    for (int m = 1; m < 64; m <<= 1) s += __shfl_xor(s, m, 64);
    int sidx = (p & 127) * 32 + (p >> 7);
    bf16x4 c0, c1;
    c0[0] = (__bf16)a.x; c0[1] = (__bf16)a.y; c0[2] = (__bf16)a.z; c0[3] = (__bf16)a.w;
    c1[0] = (__bf16)b.x; c1[1] = (__bf16)b.y; c1[2] = (__bf16)b.z; c1[3] = (__bf16)b.w;
    *(bf16x4*)(pB + (size_t)sidx * DK + ln * 4) = c0;
    *(bf16x4*)(pB + (size_t)sidx * DK + 256 + ln * 4) = c1;
    if (ln == 0) p_sq[sidx] = s * L2E;
}

// ---------------------------------------------------------------------------
// K2: barrier-free fused GEMM + online LSE. Each wave owns 64 rows (A
// resident in 256 VGPRs) and streams its 512-proto slice as 16-proto
// B-fragments loaded DIRECTLY global->register (one dwordx4 per lane,
// line-coalesced), double-buffered in two 8-frag halves. No LDS for A/B,
// no __syncthreads in the main loop — per-wave counted vmcnt only.
// Deferred-LSE: group g-1's z (16 regs) folded as slices into group g's
// MFMA phases. Numerator: class = 2 groups -> online merge on byte-packed
// label hit-mask (EXACT carry-free zero-byte detect — the classic
// (x-0x01010101)&~x&0x80808080 trick is borrow-UNSAFE and caused R2's
// false numerator hits). SENT pseudo-group self-cleans at g=1.
// ---------------------------------------------------------------------------
__global__ __launch_bounds__(256, 1) void k_main(
        const float* __restrict__ feat,
        const __bf16* __restrict__ pB,
        const float* __restrict__ p_sq,    // sorted, pre-scaled by log2(e)
        const int* __restrict__ label,
        float4* __restrict__ part) {

    __shared__ float sPsq[PPB];            // 2 KB — only LDS in the kernel

    const int t    = threadIdx.x;
    const int w    = t >> 6;
    const int l    = t & 63;
    const int ln   = l & 15;
    const int quad = l >> 4;
    const int bx   = blockIdx.x;
    const int gy   = blockIdx.y;
    const int rw   = bx * 256 + w * 64;    // wave owns 64 rows
    const int p0   = gy * PPB;

    sPsq[t]       = p_sq[p0 + t];
    sPsq[t + 256] = p_sq[p0 + t + 256];

    // packed labels: byte r of labs[mf] = label(row rw + mf*16 + quad*4 + r)
    unsigned labs[4];
#pragma unroll
    for (int mf = 0; mf < 4; ++mf) {
        int base = rw + mf * 16 + quad * 4;
        labs[mf] = (unsigned)label[base]
                 | ((unsigned)label[base + 1] << 8)
                 | ((unsigned)label[base + 2] << 16)
                 | ((unsigned)label[base + 3] << 24);
    }

    // ---- A resident: 64 rows x 512 dims, f32 -> bf16 in-register ----
    bf16x8 afrag[4][16];
#pragma unroll
    for (int mf = 0; mf < 4; ++mf) {
        const float* ar = feat + (size_t)(rw + mf * 16 + ln) * DK + quad * 8;
#pragma unroll
        for (int ks = 0; ks < 16; ++ks) {
            float4 u = *(const float4*)(ar + ks * 32);
            float4 v = *(const float4*)(ar + ks * 32 + 4);
            bf16x8 c;
            c[0] = (__bf16)u.x; c[1] = (__bf16)u.y; c[2] = (__bf16)u.z; c[3] = (__bf16)u.w;
            c[4] = (__bf16)v.x; c[5] = (__bf16)v.y; c[6] = (__bf16)v.z; c[7] = (__bf16)v.w;
            afrag[mf][ks] = c;
        }
    }

    __syncthreads();                       // sPsq ready; last barrier

    // per-lane B base: proto p0+ln, k-chunk quad*8
    const __bf16* bp = pB + (size_t)(p0 + ln) * DK + quad * 8;

    // preload group 0 into the two half-buffers
    bf16x8 b0[8], b1[8];
#pragma unroll
    for (int ks = 0; ks < 8; ++ks) b0[ks] = *(const bf16x8*)(bp + ks * 32);
#pragma unroll
    for (int ks = 0; ks < 8; ++ks) b1[ks] = *(const bf16x8*)(bp + 256 + ks * 32);

    // online state (log2 domain) + deferred-z pipeline
    float Md[4][4], Sd[4][4], Mn[4][4], Sn[4][4], zp[4][4];
    unsigned hmp[4];
    f32x4 acc[4];
#pragma unroll
    for (int mf = 0; mf < 4; ++mf) {
        hmp[mf] = 0u;
        acc[mf] = (f32x4){0.f, 0.f, 0.f, 0.f};
#pragma unroll
        for (int r = 0; r < 4; ++r) {
            Md[mf][r] = SENT; Sd[mf][r] = 0.f;
            Mn[mf][r] = SENT; Sn[mf][r] = 0.f;
            zp[mf][r] = SENT;
        }
    }

#define DEN_SLICE(j) {                                                     \
        const int mfj = (j) >> 2, rj = (j) & 3;                            \
        float z  = zp[mfj][rj];                                            \
        float nm = fmaxf(Md[mfj][rj], z);                                  \
        Sd[mfj][rj] = fmaf(Sd[mfj][rj], ex2(Md[mfj][rj] - nm), ex2(z - nm)); \
        Md[mfj][rj] = nm; }

#define NUM_MERGE() {                                                      \
        int anyp = (int)(hmp[0] | hmp[1] | hmp[2] | hmp[3]);               \
        if (__any(anyp != 0)) {                                            \
            _Pragma("unroll")                                              \
            for (int mf = 0; mf < 4; ++mf)                                 \
            { _Pragma("unroll")                                            \
              for (int r = 0; r < 4; ++r) {                                \
                bool hit = (hmp[mf] >> (8 * r + 7)) & 1;                   \
                float z  = zp[mf][r];                                      \
                float nm = fmaxf(Mn[mf][r], z);                            \
                float sn = fmaf(Sn[mf][r], ex2(Mn[mf][r] - nm), ex2(z - nm)); \
                Mn[mf][r] = hit ? nm : Mn[mf][r];                          \
                Sn[mf][r] = hit ? sn : Sn[mf][r];                          \
            } } } }

#pragma unroll 1
    for (int g = 0; g < NG; ++g) {
        const __bf16* bn = bp + (size_t)(g + 1) * (PG * DK);
        float nps = -sPsq[g * PG + ln];

        // ---- phase A: MFMA ks 0..7 on b0, + prev-group LSE slices 0..7 ----
#pragma unroll
        for (int ks = 0; ks < 8; ++ks) {
            acc[0] = __builtin_amdgcn_mfma_f32_16x16x32_bf16(afrag[0][ks], b0[ks], acc[0], 0, 0, 0);
            acc[1] = __builtin_amdgcn_mfma_f32_16x16x32_bf16(afrag[1][ks], b0[ks], acc[1], 0, 0, 0);
            acc[2] = __builtin_amdgcn_mfma_f32_16x16x32_bf16(afrag[2][ks], b0[ks], acc[2], 0, 0, 0);
            acc[3] = __builtin_amdgcn_mfma_f32_16x16x32_bf16(afrag[3][ks], b0[ks], acc[3], 0, 0, 0);
            DEN_SLICE(ks);
        }
        // refill b0 with group g+1 first half (latency hidden under phase B)
        if (g + 1 < NG) {
#pragma unroll
            for (int ks = 0; ks < 8; ++ks) b0[ks] = *(const bf16x8*)(bn + ks * 32);
        }

        // ---- phase B: MFMA ks 8..15 on b1, + slices 8..15 ----
#pragma unroll
        for (int ks = 0; ks < 8; ++ks) {
            acc[0] = __builtin_amdgcn_mfma_f32_16x16x32_bf16(afrag[0][ks + 8], b1[ks], acc[0], 0, 0, 0);
            acc[1] = __builtin_amdgcn_mfma_f32_16x16x32_bf16(afrag[1][ks + 8], b1[ks], acc[1], 0, 0, 0);
            acc[2] = __builtin_amdgcn_mfma_f32_16x16x32_bf16(afrag[2][ks + 8], b1[ks], acc[2], 0, 0, 0);
            acc[3] = __builtin_amdgcn_mfma_f32_16x16x32_bf16(afrag[3][ks + 8], b1[ks], acc[3], 0, 0, 0);
            DEN_SLICE(ks + 8);
        }
        if (g + 1 < NG) {
#pragma unroll
            for (int ks = 0; ks < 8; ++ks) b1[ks] = *(const bf16x8*)(bn + 256 + ks * 32);
        }

        // ---- numerator merge for group g-1 (zp still holds its z) ----
        NUM_MERGE();

        // ---- z(g) -> pipeline regs; reset acc; hit-mask for group g ----
        const unsigned cmul = (unsigned)(gy * 16 + (g >> 1)) * 0x01010101u;
#pragma unroll
        for (int mf = 0; mf < 4; ++mf) {
#pragma unroll
            for (int r = 0; r < 4; ++r)
                zp[mf][r] = fmaf(acc[mf][r], 2.0f * L2E, nps);
            acc[mf] = (f32x4){0.f, 0.f, 0.f, 0.f};
            // EXACT carry-free zero-byte detect: bit 8r+7 set iff byte r == 0
            unsigned x = labs[mf] ^ cmul;
            hmp[mf] = ~(((x & 0x7F7F7F7Fu) + 0x7F7F7F7Fu) | x | 0x7F7F7F7Fu);
        }
    }

    // ---- epilogue: fold the last group's deferred z ----
#pragma unroll
    for (int j = 0; j < 16; ++j) DEN_SLICE(j);
    NUM_MERGE();

#undef DEN_SLICE
#undef NUM_MERGE

    // ---- merge the 16 ln-lanes per quad, write partials ----
#pragma unroll
    for (int mf = 0; mf < 4; ++mf)
#pragma unroll
        for (int r = 0; r < 4; ++r) {
            float md = Md[mf][r], sd = Sd[mf][r];
            float mn = Mn[mf][r], sn = Sn[mf][r];
#pragma unroll
            for (int m = 1; m < 16; m <<= 1) {
                float omd = __shfl_xor(md, m, 64);
                float osd = __shfl_xor(sd, m, 64);
                float omn = __shfl_xor(mn, m, 64);
                float osn = __shfl_xor(sn, m, 64);
                float nm = fmaxf(md, omd);
                sd = sd * ex2(md - nm) + osd * ex2(omd - nm);
                md = nm;
                nm = fmaxf(mn, omn);
                sn = sn * ex2(mn - nm) + osn * ex2(omn - nm);
                mn = nm;
            }
            if (ln == 0) {
                int row = rw + mf * 16 + quad * 4 + r;
                part[row * GY + gy] = make_float4(md, sd, mn, sn);
            }
        }
}

// ---------------------------------------------------------------------------
// K3: merge the GY partials per row (log2 domain), final loss in nats
// ---------------------------------------------------------------------------
__global__ __launch_bounds__(256) void k_comb(const float4* __restrict__ part,
                                              float* __restrict__ out) {
    int row = blockIdx.x * 256 + threadIdx.x;
    float md = SENT, sd = 0.f, mn = SENT, sn = 0.f;
#pragma unroll
    for (int q = 0; q < GY; ++q) {
        float4 v = part[row * GY + q];
        float nm = fmaxf(md, v.x);
        sd = sd * ex2(md - nm) + v.y * ex2(v.x - nm);
        md = nm;
        nm = fmaxf(mn, v.z);
        sn = sn * ex2(mn - nm) + v.w * ex2(v.z - nm);
        mn = nm;
    }
    out[row] = ((md + __builtin_amdgcn_logf(sd)) - (mn + __builtin_amdgcn_logf(sn))) * LN2;
}

extern "C" void kernel_launch(void* const* d_in, const int* in_sizes, int n_in,
                              void* d_out, int out_size, void* d_ws, size_t ws_size,
                              hipStream_t stream) {
    const float* feat   = (const float*)d_in[0];
    const int*   label  = (const int*)d_in[1];
    const float* proto  = (const float*)d_in[2];
    float*       out    = (float*)d_out;

    char* w = (char*)d_ws;
    __bf16* pB    = (__bf16*)(w);                 // 4096*512*2  = 4,194,304 B
    float*  p_sq  = (float*)(w + 4194304);        // 4096*4
    float4* part  = (float4*)(w + 4243456);       // 8192*GY*16

    hipLaunchKernelGGL(k_prep, dim3(PN / 4), dim3(256), 0, stream,
                       proto, pB, p_sq);
    hipLaunchKernelGGL(k_main, dim3(BN / 256, GY), dim3(256), 0, stream,
                       feat, pB, p_sq, label, part);
    hipLaunchKernelGGL(k_comb, dim3(BN / 256), dim3(256), 0, stream,
                       part, out);
}

// Round 4
// 125.267 us; speedup vs baseline: 1.3033x; 1.3033x over previous
//
#include <hip/hip_runtime.h>
#include <hip/hip_bf16.h>

#define BN 8192
#define DK 512
#define PN 4096
#define GY 8
#define PPB 512            // protos per slice
#define CH 16              // protos per chunk (HALF a class; class = gy*16 + (nt>>1))
#define NCH 32             // chunks per slice
#define STRIDE 520         // row stride in elems (1040 B)
#define BUFELE (CH * STRIDE)   // 8320 elems = 16,640 B per ring buffer
#define SENT (-1.0e30f)
#define L2E 1.4426950408889634f
#define LN2 0.6931471805599453f

typedef __bf16 bf16x8 __attribute__((ext_vector_type(8)));
typedef __bf16 bf16x4 __attribute__((ext_vector_type(4)));
typedef float f32x4 __attribute__((ext_vector_type(4)));

__device__ __forceinline__ float ex2(float x) { return __builtin_amdgcn_exp2f(x); }

__device__ __forceinline__ void gl_lds16(const void* g, void* l) {
    __builtin_amdgcn_global_load_lds(
        (const __attribute__((address_space(1))) void*)g,
        (__attribute__((address_space(3))) void*)l, 16, 0, 0);
}

// ---------------------------------------------------------------------------
// K1: protos only — bf16 cast in CLASS-SORTED order + p_sq*log2e (sorted).
// Original proto p has class p%128; sorted row s = (p%128)*32 + p/128.
// ---------------------------------------------------------------------------
__global__ __launch_bounds__(256) void k_prep(const float* __restrict__ proto,
                                              __bf16* __restrict__ pB,
                                              float* __restrict__ p_sq) {
    int p  = blockIdx.x * 4 + (threadIdx.x >> 6);
    int ln = threadIdx.x & 63;
    const float* src = proto + (size_t)p * DK;
    float4 a = *(const float4*)(src + ln * 4);
    float4 b = *(const float4*)(src + 256 + ln * 4);
    float s = a.x * a.x + a.y * a.y + a.z * a.z + a.w * a.w
            + b.x * b.x + b.y * b.y + b.z * b.z + b.w * b.w;
#pragma unroll
    for (int m = 1; m < 64; m <<= 1) s += __shfl_xor(s, m, 64);
    int sidx = (p & 127) * 32 + (p >> 7);
    bf16x4 c0, c1;
    c0[0] = (__bf16)a.x; c0[1] = (__bf16)a.y; c0[2] = (__bf16)a.z; c0[3] = (__bf16)a.w;
    c1[0] = (__bf16)b.x; c1[1] = (__bf16)b.y; c1[2] = (__bf16)b.z; c1[3] = (__bf16)b.w;
    *(bf16x4*)(pB + (size_t)sidx * DK + ln * 4) = c0;
    *(bf16x4*)(pB + (size_t)sidx * DK + 256 + ln * 4) = c1;
    if (ln == 0) p_sq[sidx] = s * L2E;
}

// ---------------------------------------------------------------------------
// K2: fused GEMM + online LSE (log2 domain). R1 structure (LDS-staged B,
// A resident 32 rows/wave, deferred-LSE interleave) with the chunk loop
// rebuilt as a 4-buffer ring of 16-proto chunks driven by raw s_barrier +
// counted `s_waitcnt vmcnt(8)` (T3+T4): the wait targets loads issued 3
// iterations earlier, so the per-chunk vmcnt(0) barrier-drain of the
// __syncthreads version disappears. Tail peeled at vmcnt(4)/vmcnt(0).
// ---------------------------------------------------------------------------
__global__ __launch_bounds__(256, 2) void k_main(
        const float* __restrict__ feat,
        const __bf16* __restrict__ pB,
        const float* __restrict__ p_sq,    // sorted, pre-scaled by log2(e)
        const int* __restrict__ label,
        float4* __restrict__ part) {

    __shared__ __bf16 sM[4 * BUFELE];      // 66,560 B; bufs 2,3 double as A staging
    __shared__ float  sPsq[PPB];           // 2 KB

    const int t    = threadIdx.x;
    const int w    = t >> 6;
    const int l    = t & 63;
    const int ln   = l & 15;
    const int quad = l >> 4;
    const int bx   = blockIdx.x;
    const int gy   = blockIdx.y;
    const int rw   = bx * 128 + w * 32;
    const int p0   = gy * PPB;

    int lab[2][4];
#pragma unroll
    for (int mf = 0; mf < 2; ++mf)
#pragma unroll
        for (int r = 0; r < 4; ++r)
            lab[mf][r] = label[rw + mf * 16 + quad * 4 + r];

    // issue chunk c: 16 proto rows, each wave stages 4 rows (wave-uniform LDS base)
#define ISSUE(c) {                                                          \
        const __bf16* g = pB + (size_t)(p0 + (c) * CH + w * 4) * DK + l * 8; \
        __bf16* lp = sM + ((c) & 3) * BUFELE + (w * 4) * STRIDE;            \
        _Pragma("unroll")                                                   \
        for (int j = 0; j < 4; ++j)                                         \
            gl_lds16(g + j * DK, lp + j * STRIDE);                          \
    }

    // ---- chunk-0 prefetch into buf0 FIRST (lands during A staging) ----
    ISSUE(0);
    sPsq[t]       = p_sq[p0 + t];
    sPsq[t + 256] = p_sq[p0 + t + 256];

    // ---- stage A in 32-row quarters through bufs 2,3; frags -> 128 VGPRs ----
    __bf16* sA = sM + 2 * BUFELE;
    bf16x8 afrag[2][16];
#pragma unroll 1
    for (int q = 0; q < 4; ++q) {
#pragma unroll 4
        for (int i = 0; i < 16; ++i) {
            int idx = t + 256 * i;
            int row = idx >> 7;        // 0..31
            int c4  = idx & 127;
            float4 v = *(const float4*)(feat + (size_t)(bx * 128 + q * 32 + row) * DK + c4 * 4);
            bf16x4 cv;
            cv[0] = (__bf16)v.x; cv[1] = (__bf16)v.y; cv[2] = (__bf16)v.z; cv[3] = (__bf16)v.w;
            *(bf16x4*)(sA + row * STRIDE + c4 * 4) = cv;
        }
        __syncthreads();
        if (w == q) {
#pragma unroll
            for (int mf = 0; mf < 2; ++mf)
#pragma unroll
                for (int ks = 0; ks < 16; ++ks)
                    afrag[mf][ks] = *(const bf16x8*)(sA + (mf * 16 + ln) * STRIDE + ks * 32 + quad * 8);
        }
        __syncthreads();               // drains vmcnt too: chunk 0 has landed
    }

    // ---- fill the ring: chunks 1,2 (overwrites A-staging area — all waves done) ----
    ISSUE(1);
    ISSUE(2);

    // ---- online state (log2 domain) + deferred-z pipeline ----
    float Md[2][4], Sd[2][4], Mn[2][4], Sn[2][4], zp[2][4];
#pragma unroll
    for (int mf = 0; mf < 2; ++mf)
#pragma unroll
        for (int r = 0; r < 4; ++r) {
            Md[mf][r] = SENT; Sd[mf][r] = 0.f;
            Mn[mf][r] = SENT; Sn[mf][r] = 0.f;
            zp[mf][r] = SENT;
        }
    int clsp = -1;                     // class of previous chunk (chunk -1: no hit)

#define DEN_SLICE(j) {                                                      \
        const int mfj = (j) >> 2, rj = (j) & 3;                             \
        float z  = zp[mfj][rj];                                             \
        float nm = fmaxf(Md[mfj][rj], z);                                   \
        Sd[mfj][rj] = fmaf(Sd[mfj][rj], ex2(Md[mfj][rj] - nm), ex2(z - nm)); \
        Md[mfj][rj] = nm; }

#define NUM_MERGE() {                                                       \
        int anyhit = 0;                                                     \
        _Pragma("unroll")                                                   \
        for (int mf = 0; mf < 2; ++mf)                                      \
        { _Pragma("unroll")                                                 \
          for (int r = 0; r < 4; ++r) anyhit |= (clsp == lab[mf][r]); }     \
        if (__any(anyhit)) {                                                \
            _Pragma("unroll")                                               \
            for (int mf = 0; mf < 2; ++mf)                                  \
            { _Pragma("unroll")                                             \
              for (int r = 0; r < 4; ++r) {                                 \
                bool hit = (clsp == lab[mf][r]);                            \
                float z  = zp[mf][r];                                       \
                float nm = fmaxf(Mn[mf][r], z);                             \
                float sn = fmaf(Sn[mf][r], ex2(Mn[mf][r] - nm), ex2(z - nm)); \
                Mn[mf][r] = hit ? nm : Mn[mf][r];                           \
                Sn[mf][r] = hit ? sn : Sn[mf][r];                           \
            } } } }

    // compute chunk nt from buf[nt&3]; fold prev chunk's LSE into the MFMA loop
#define COMPUTE(nt) {                                                       \
        const __bf16* sB = sM + ((nt) & 3) * BUFELE;                        \
        float nps = -sPsq[(nt) * CH + ln];                                  \
        f32x4 a0 = (f32x4){0.f, 0.f, 0.f, 0.f};                             \
        f32x4 a1 = (f32x4){0.f, 0.f, 0.f, 0.f};                             \
        _Pragma("unroll")                                                   \
        for (int ks = 0; ks < 16; ++ks) {                                   \
            bf16x8 b = *(const bf16x8*)(sB + ln * STRIDE + ks * 32 + quad * 8); \
            a0 = __builtin_amdgcn_mfma_f32_16x16x32_bf16(afrag[0][ks], b, a0, 0, 0, 0); \
            a1 = __builtin_amdgcn_mfma_f32_16x16x32_bf16(afrag[1][ks], b, a1, 0, 0, 0); \
            if ((ks & 1) == 0) DEN_SLICE(ks >> 1);                          \
        }                                                                   \
        NUM_MERGE();                                                        \
        _Pragma("unroll")                                                   \
        for (int r = 0; r < 4; ++r) {                                       \
            zp[0][r] = fmaf(a0[r], 2.0f * L2E, nps);                        \
            zp[1][r] = fmaf(a1[r], 2.0f * L2E, nps);                        \
        }                                                                   \
        clsp = gy * 16 + ((nt) >> 1); }

    // ---- main ring loop: wait(counted) -> barrier -> issue nt+3 -> compute nt ----
#pragma unroll 1
    for (int nt = 0; nt < NCH - 2; ++nt) {
        asm volatile("s_waitcnt vmcnt(8)" ::: "memory");   // chunk nt landed (ours)
        __builtin_amdgcn_s_barrier();                      // everyone's landed; nt-1 free
        if (nt + 3 < NCH) ISSUE(nt + 3);                   // into buf[(nt-1)&3]
        COMPUTE(nt);
    }
    // ---- peeled tail: fewer loads in flight => tighter counts ----
    asm volatile("s_waitcnt vmcnt(4)" ::: "memory");
    __builtin_amdgcn_s_barrier();
    COMPUTE(NCH - 2);
    asm volatile("s_waitcnt vmcnt(0)" ::: "memory");
    __builtin_amdgcn_s_barrier();
    COMPUTE(NCH - 1);

    // ---- epilogue: fold the last chunk's deferred z ----
#pragma unroll
    for (int j = 0; j < 8; ++j) DEN_SLICE(j);
    NUM_MERGE();

#undef COMPUTE
#undef DEN_SLICE
#undef NUM_MERGE
#undef ISSUE

    // ---- merge 16 lanes per quad-group, write partials ----
#pragma unroll
    for (int mf = 0; mf < 2; ++mf)
#pragma unroll
        for (int r = 0; r < 4; ++r) {
            float md = Md[mf][r], sd = Sd[mf][r];
            float mn = Mn[mf][r], sn = Sn[mf][r];
#pragma unroll
            for (int m = 1; m < 16; m <<= 1) {
                float omd = __shfl_xor(md, m, 64);
                float osd = __shfl_xor(sd, m, 64);
                float omn = __shfl_xor(mn, m, 64);
                float osn = __shfl_xor(sn, m, 64);
                float nm = fmaxf(md, omd);
                sd = sd * ex2(md - nm) + osd * ex2(omd - nm);
                md = nm;
                nm = fmaxf(mn, omn);
                sn = sn * ex2(mn - nm) + osn * ex2(omn - nm);
                mn = nm;
            }
            if (ln == 0) {
                int row = rw + mf * 16 + quad * 4 + r;
                part[row * GY + gy] = make_float4(md, sd, mn, sn);
            }
        }
}

// ---------------------------------------------------------------------------
// K3: merge the GY partials per row (log2 domain), final loss in nats
// ---------------------------------------------------------------------------
__global__ __launch_bounds__(256) void k_comb(const float4* __restrict__ part,
                                              float* __restrict__ out) {
    int row = blockIdx.x * 256 + threadIdx.x;
    float md = SENT, sd = 0.f, mn = SENT, sn = 0.f;
#pragma unroll
    for (int q = 0; q < GY; ++q) {
        float4 v = part[row * GY + q];
        float nm = fmaxf(md, v.x);
        sd = sd * ex2(md - nm) + v.y * ex2(v.x - nm);
        md = nm;
        nm = fmaxf(mn, v.z);
        sn = sn * ex2(mn - nm) + v.w * ex2(v.z - nm);
        mn = nm;
    }
    out[row] = ((md + __builtin_amdgcn_logf(sd)) - (mn + __builtin_amdgcn_logf(sn))) * LN2;
}

extern "C" void kernel_launch(void* const* d_in, const int* in_sizes, int n_in,
                              void* d_out, int out_size, void* d_ws, size_t ws_size,
                              hipStream_t stream) {
    const float* feat   = (const float*)d_in[0];
    const int*   label  = (const int*)d_in[1];
    const float* proto  = (const float*)d_in[2];
    float*       out    = (float*)d_out;

    char* w = (char*)d_ws;
    __bf16* pB    = (__bf16*)(w);                 // 4096*512*2  = 4,194,304 B
    float*  p_sq  = (float*)(w + 4194304);        // 4096*4
    float4* part  = (float4*)(w + 4243456);       // 8192*GY*16

    hipLaunchKernelGGL(k_prep, dim3(PN / 4), dim3(256), 0, stream,
                       proto, pB, p_sq);
    hipLaunchKernelGGL(k_main, dim3(64, GY), dim3(256), 0, stream,
                       feat, pB, p_sq, label, part);
    hipLaunchKernelGGL(k_comb, dim3(BN / 256), dim3(256), 0, stream,
                       part, out);
}